// Round 2
// baseline (3499.992 us; speedup 1.0000x reference)
//
#include <hip/hip_runtime.h>
#include <hip/hip_bf16.h>

typedef unsigned short u16;
typedef unsigned int   u32;

// ---- bf16 helpers (bit-level) ----
__device__ __forceinline__ float b2f(u16 v) {
    union { u32 i; float f; } u; u.i = ((u32)v) << 16; return u.f;
}
__device__ __forceinline__ float blo(u32 v) {
    union { u32 i; float f; } u; u.i = v << 16; return u.f;
}
__device__ __forceinline__ float bhi(u32 v) {
    union { u32 i; float f; } u; u.i = v & 0xffff0000u; return u.f;
}
__device__ __forceinline__ u16 f2b(float f) {   // RNE f32 -> bf16
    u32 x = __float_as_uint(f);
    u32 r = (x + 0x7fffu + ((x >> 16) & 1u)) >> 16;
    return (u16)r;
}

// ---- dtype-generic accessors ----
template<bool BF16>
__device__ __forceinline__ float g_at(const void* p, size_t i) {
    if constexpr (BF16) return b2f(((const u16*)p)[i]);
    else                return ((const float*)p)[i];
}
template<bool BF16>
__device__ __forceinline__ float2 g_at2(const void* p, size_t i) {  // i even
    if constexpr (BF16) { u32 v = ((const u32*)p)[i >> 1]; return make_float2(blo(v), bhi(v)); }
    else                return ((const float2*)p)[i >> 1];
}
template<bool BF16>
__device__ __forceinline__ void g_st(void* p, size_t i, float v) {
    if constexpr (BF16) ((u16*)p)[i] = f2b(v);
    else                ((float*)p)[i] = v;
}

// Detect packed-bf16 vs fp32 from the boxes buffer: box values are in (0,1].
// If bf16-packed, every low u16 of the first 8 u32 words is a positive bf16
// <= 1.0, i.e. <= 0x3F80. For fp32 data the low u16 is random mantissa bits;
// P(all 16 halves pass) ~= 2e-10.
__device__ __forceinline__ bool detect_bf16(const void* boxes) {
    const u32* u = (const u32*)boxes;
    bool ok = true;
#pragma unroll
    for (int i = 0; i < 8; ++i) ok = ok && ((u[i] & 0xFFFFu) <= 0x3F80u);
    return ok;
}

#define HW 512
#define CIN 64
#define ZCROP (16*16*64)   // zero-pad tail index in s_crop
#define ZC1   (8*8*128)    // zero-pad tail index in s_c1

template<bool BF16>
__global__ __launch_bounds__(256, 2) void mask_head(
    const void* __restrict__ feat, const void* __restrict__ prop,
    const void* __restrict__ boxes, const int* __restrict__ bidx,
    const int* __restrict__ cls,
    const void* __restrict__ w1, const void* __restrict__ b1,
    const void* __restrict__ w2, const void* __restrict__ b2,
    const void* __restrict__ wd1, const void* __restrict__ bd1,
    const void* __restrict__ wd2, const void* __restrict__ bd2,
    const void* __restrict__ wr, const void* __restrict__ br,
    const void* __restrict__ wsc, const void* __restrict__ bsc,
    void* __restrict__ out, int N)
{
    // self-gate on detected dtype (block-uniform, before any barrier)
    if (detect_bf16(boxes) != BF16) return;

    __shared__ __align__(16) u16  s_crop[ZCROP + 128]; // 16x16x64 bf16 + zero pad
    __shared__ __align__(16) u16  s_c1[ZC1 + 128];     // 8x8x128 bf16 + zero pad
    __shared__ __align__(16) float s_c2[2048];         // 4x4x128 f32
    __shared__ __align__(16) float s_d1[512];
    __shared__ __align__(16) float s_d2[512];
    __shared__ float s_prop[256];
    __shared__ float s_wy[16], s_wx[16];
    __shared__ int   s_y0[16], s_y1[16], s_x0[16], s_x1[16];
    __shared__ float s_reg[12], s_sc[3];

    const int n = blockIdx.x;
    if (n >= N) return;
    const int t = threadIdx.x;
    const int b = bidx[n];

    const float fy1 = g_at<BF16>(boxes, n*4+0);
    const float fx1 = g_at<BF16>(boxes, n*4+1);
    const float fy2 = g_at<BF16>(boxes, n*4+2);
    const float fx2 = g_at<BF16>(boxes, n*4+3);

    // ---- bilinear sampling grid (TF crop_and_resize semantics) ----
    if (t < 16) {
        float g = (float)t * (1.0f / 15.0f);
        float yy = (fy1 + g * (fy2 - fy1)) * (float)(HW - 1);
        float xx = (fx1 + g * (fx2 - fx1)) * (float)(HW - 1);
        float yf = floorf(yy), xf = floorf(xx);
        s_wy[t] = yy - yf;  s_wx[t] = xx - xf;
        int y0 = min(max((int)yf, 0), HW-1);
        int x0 = min(max((int)xf, 0), HW-1);
        s_y0[t] = y0; s_y1[t] = min(y0 + 1, HW-1);
        s_x0[t] = x0; s_x1[t] = min(x0 + 1, HW-1);
    }
    // zero the pad tails
    if (t >= 128) s_crop[ZCROP + (t - 128)] = 0;
    if (t < 128)  s_c1[ZC1 + t] = 0;
    __syncthreads();

    // ---- proposal crop (one pixel per thread) ----
    {
        int py = t >> 4, px = t & 15;
        size_t pb = (size_t)b * (HW * HW);
        int y0 = s_y0[py], y1 = s_y1[py], x0 = s_x0[px], x1 = s_x1[px];
        float wy = s_wy[py], wx = s_wx[px];
        float p00 = g_at<BF16>(prop, pb + y0*HW + x0);
        float p01 = g_at<BF16>(prop, pb + y0*HW + x1);
        float p10 = g_at<BF16>(prop, pb + y1*HW + x0);
        float p11 = g_at<BF16>(prop, pb + y1*HW + x1);
        float top = p00 * (1.0f - wx) + p01 * wx;
        float bot = p10 * (1.0f - wx) + p11 * wx;
        s_prop[t] = top * (1.0f - wy) + bot * wy;
    }
    __syncthreads();

    // ---- feature crop * proposal -> LDS (bf16) ----
    {
        size_t fb = (size_t)b * ((size_t)HW * HW * CIN);
        const int ch = t & 63;
        const int wvl = t >> 6;
        for (int it = 0; it < 64; ++it) {
            int pix = it * 4 + wvl;            // wave-uniform pixel
            int py = pix >> 4, px = pix & 15;
            int y0 = s_y0[py], y1 = s_y1[py], x0 = s_x0[px], x1 = s_x1[px];
            float wy = s_wy[py], wx = s_wx[px];
            float f00 = g_at<BF16>(feat, fb + (size_t)(y0*HW + x0)*CIN + ch);
            float f01 = g_at<BF16>(feat, fb + (size_t)(y0*HW + x1)*CIN + ch);
            float f10 = g_at<BF16>(feat, fb + (size_t)(y1*HW + x0)*CIN + ch);
            float f11 = g_at<BF16>(feat, fb + (size_t)(y1*HW + x1)*CIN + ch);
            float top = f00 * (1.0f - wx) + f01 * wx;
            float bot = f10 * (1.0f - wx) + f11 * wx;
            float v = (top * (1.0f - wy) + bot * wy) * s_prop[pix];
            s_crop[pix * 64 + ch] = f2b(v);
        }
    }
    __syncthreads();

    const int ocp = t & 63;   // output-channel pair index
    const int wv  = t >> 6;

    // ---- conv1: 16x16x64 -> 8x8x128, 3x3 stride 2, SAME (pad hi only) ----
    {
        float2 bb = g_at2<BF16>(b1, 2*ocp);
        for (int it = 0; it < 4; ++it) {
            int g = it * 4 + wv;              // 0..15
            int oy = g >> 1;
            int oxb = (g & 1) * 4;
            float acc[4][2];
            #pragma unroll
            for (int p = 0; p < 4; ++p) { acc[p][0] = 0.f; acc[p][1] = 0.f; }
            #pragma unroll
            for (int ky = 0; ky < 3; ++ky) {
                int y = oy * 2 + ky;
                bool yv = (y < 16);
                #pragma unroll
                for (int kx = 0; kx < 3; ++kx) {
                    int off[4];
                    #pragma unroll
                    for (int p = 0; p < 4; ++p) {
                        int x = (oxb + p) * 2 + kx;
                        off[p] = (yv && x < 16) ? (y*16 + x) * 64 : ZCROP;
                    }
                    size_t wbase = ((size_t)(ky*3 + kx) * 64) * 128 + 2*ocp;
                    #pragma unroll 8
                    for (int ci = 0; ci < 64; ci += 2) {
                        float2 wa = g_at2<BF16>(w1, wbase + (size_t)ci*128);
                        float2 wb = g_at2<BF16>(w1, wbase + (size_t)(ci+1)*128);
                        #pragma unroll
                        for (int p = 0; p < 4; ++p) {
                            u32 cc = *(const u32*)&s_crop[off[p] + ci];
                            float v0 = blo(cc), v1 = bhi(cc);
                            acc[p][0] += v0 * wa.x + v1 * wb.x;
                            acc[p][1] += v0 * wa.y + v1 * wb.y;
                        }
                    }
                }
            }
            #pragma unroll
            for (int p = 0; p < 4; ++p) {
                int opix = oy * 8 + oxb + p;
                s_c1[opix * 128 + 2*ocp    ] = f2b(fmaxf(acc[p][0] + bb.x, 0.f));
                s_c1[opix * 128 + 2*ocp + 1] = f2b(fmaxf(acc[p][1] + bb.y, 0.f));
            }
        }
    }
    __syncthreads();

    // ---- conv2: 8x8x128 -> 4x4x128 ----
    {
        float2 bb = g_at2<BF16>(b2, 2*ocp);
        int oy = wv;                           // 0..3
        float acc[4][2];
        #pragma unroll
        for (int p = 0; p < 4; ++p) { acc[p][0] = 0.f; acc[p][1] = 0.f; }
        #pragma unroll
        for (int ky = 0; ky < 3; ++ky) {
            int y = oy * 2 + ky;
            bool yv = (y < 8);
            #pragma unroll
            for (int kx = 0; kx < 3; ++kx) {
                int off[4];
                #pragma unroll
                for (int p = 0; p < 4; ++p) {
                    int x = p * 2 + kx;
                    off[p] = (yv && x < 8) ? (y*8 + x) * 128 : ZC1;
                }
                size_t wbase = ((size_t)(ky*3 + kx) * 128) * 128 + 2*ocp;
                #pragma unroll 8
                for (int ci = 0; ci < 128; ci += 2) {
                    float2 wa = g_at2<BF16>(w2, wbase + (size_t)ci*128);
                    float2 wb = g_at2<BF16>(w2, wbase + (size_t)(ci+1)*128);
                    #pragma unroll
                    for (int p = 0; p < 4; ++p) {
                        u32 cc = *(const u32*)&s_c1[off[p] + ci];
                        float v0 = blo(cc), v1 = bhi(cc);
                        acc[p][0] += v0 * wa.x + v1 * wb.x;
                        acc[p][1] += v0 * wa.y + v1 * wb.y;
                    }
                }
            }
        }
        #pragma unroll
        for (int p = 0; p < 4; ++p) {
            int opix = oy * 4 + p;
            s_c2[opix * 128 + 2*ocp    ] = fmaxf(acc[p][0] + bb.x, 0.f);
            s_c2[opix * 128 + 2*ocp + 1] = fmaxf(acc[p][1] + bb.y, 0.f);
        }
    }
    __syncthreads();

    // ---- d1: 2048 -> 512 (thread t computes outputs 2t, 2t+1) ----
    {
        float acc0 = 0.f, acc1 = 0.f;
        for (int i = 0; i < 2048; i += 4) {
            float4 xv = *(const float4*)&s_c2[i];
            float2 u0 = g_at2<BF16>(wd1, (size_t)(i+0)*512 + 2*t);
            float2 u1 = g_at2<BF16>(wd1, (size_t)(i+1)*512 + 2*t);
            float2 u2 = g_at2<BF16>(wd1, (size_t)(i+2)*512 + 2*t);
            float2 u3 = g_at2<BF16>(wd1, (size_t)(i+3)*512 + 2*t);
            acc0 += xv.x*u0.x + xv.y*u1.x + xv.z*u2.x + xv.w*u3.x;
            acc1 += xv.x*u0.y + xv.y*u1.y + xv.z*u2.y + xv.w*u3.y;
        }
        float2 bb = g_at2<BF16>(bd1, 2*t);
        s_d1[2*t    ] = fmaxf(acc0 + bb.x, 0.f);
        s_d1[2*t + 1] = fmaxf(acc1 + bb.y, 0.f);
    }
    __syncthreads();

    // ---- d2: 512 -> 512 ----
    {
        float acc0 = 0.f, acc1 = 0.f;
        for (int i = 0; i < 512; i += 4) {
            float4 xv = *(const float4*)&s_d1[i];
            float2 u0 = g_at2<BF16>(wd2, (size_t)(i+0)*512 + 2*t);
            float2 u1 = g_at2<BF16>(wd2, (size_t)(i+1)*512 + 2*t);
            float2 u2 = g_at2<BF16>(wd2, (size_t)(i+2)*512 + 2*t);
            float2 u3 = g_at2<BF16>(wd2, (size_t)(i+3)*512 + 2*t);
            acc0 += xv.x*u0.x + xv.y*u1.x + xv.z*u2.x + xv.w*u3.x;
            acc1 += xv.x*u0.y + xv.y*u1.y + xv.z*u2.y + xv.w*u3.y;
        }
        float2 bb = g_at2<BF16>(bd2, 2*t);
        s_d2[2*t    ] = fmaxf(acc0 + bb.x, 0.f);
        s_d2[2*t + 1] = fmaxf(acc1 + bb.y, 0.f);
    }
    __syncthreads();

    // ---- heads: reg (12) and score (3) ----
    if (t < 12) {
        float a = g_at<BF16>(br, t);
        for (int i = 0; i < 512; ++i) a += s_d2[i] * g_at<BF16>(wr, (size_t)i*12 + t);
        s_reg[t] = a;
    }
    if (t >= 64 && t < 67) {
        int j = t - 64;
        float a = g_at<BF16>(bsc, j);
        for (int i = 0; i < 512; ++i) a += s_d2[i] * g_at<BF16>(wsc, (size_t)i*3 + j);
        s_sc[j] = a;
    }
    __syncthreads();

    // ---- gather by cls, recover boxes, write outputs ----
    if (t == 0) {
        int c = cls[n];
        g_st<BF16>(out, n, s_sc[c]);                       // scores [4096]
        float dy = s_reg[c*4+0], dx = s_reg[c*4+1];
        float dh = s_reg[c*4+2], dw = s_reg[c*4+3];
        g_st<BF16>(out, 4096 + n*4 + 0, dy);               // regressions [4096,4]
        g_st<BF16>(out, 4096 + n*4 + 1, dx);
        g_st<BF16>(out, 4096 + n*4 + 2, dh);
        g_st<BF16>(out, 4096 + n*4 + 3, dw);
        float h = fy2 - fy1, w = fx2 - fx1;
        float cy = fy1 + 0.5f*h + dy*h;
        float cx = fx1 + 0.5f*w + dx*w;
        float nh = h * expf(dh);
        float nw = w * expf(dw);
        g_st<BF16>(out, 20480 + n*4 + 0, cy - 0.5f*nh);    // bboxes [4096,4]
        g_st<BF16>(out, 20480 + n*4 + 1, cx - 0.5f*nw);
        g_st<BF16>(out, 20480 + n*4 + 2, cy + 0.5f*nh);
        g_st<BF16>(out, 20480 + n*4 + 3, cx + 0.5f*nw);
    }
}

extern "C" void kernel_launch(void* const* d_in, const int* in_sizes, int n_in,
                              void* d_out, int out_size, void* d_ws, size_t ws_size,
                              hipStream_t stream) {
    const void* feat  = d_in[0];
    const void* prop  = d_in[1];
    const void* boxes = d_in[2];
    const int*  bidx  = (const int*)d_in[3];
    const int*  cls   = (const int*)d_in[4];
    const void* w1  = d_in[5];
    const void* b1  = d_in[6];
    const void* w2  = d_in[7];
    const void* b2  = d_in[8];
    const void* wd1 = d_in[9];
    const void* bd1 = d_in[10];
    const void* wd2 = d_in[11];
    const void* bd2 = d_in[12];
    const void* wr  = d_in[13];
    const void* br  = d_in[14];
    const void* wsc = d_in[15];
    const void* bsc = d_in[16];
    const int N = in_sizes[3];   // 4096 boxes

    // Launch both dtype interpretations; each instance self-gates per block on
    // a cheap runtime detector (wrong-dtype instance returns immediately).
    mask_head<true ><<<N, 256, 0, stream>>>(feat, prop, boxes, bidx, cls,
                                            w1, b1, w2, b2, wd1, bd1, wd2, bd2,
                                            wr, br, wsc, bsc, d_out, N);
    mask_head<false><<<N, 256, 0, stream>>>(feat, prop, boxes, bidx, cls,
                                            w1, b1, w2, b2, wd1, bd1, wd2, bd2,
                                            wr, br, wsc, bsc, d_out, N);
}